// Round 9
// baseline (122.533 us; speedup 1.0000x reference)
//
#include <hip/hip_runtime.h>
#include <math.h>

constexpr int Nn = 16384;
constexpr int ST = 68;                      // ws row stride (dwords): 64 qk + 4 pp
constexpr size_t NS = (size_t)Nn * 16;      // dwords per channel plane of npts

// ---- DPP helpers (pure VALU cross-lane, rows of 16) ----
template <int CTRL>
__device__ __forceinline__ float dpp_f(float x) {
    return __int_as_float(
        __builtin_amdgcn_update_dpp(0, __float_as_int(x), CTRL, 0xF, 0xF, false));
}
__device__ __forceinline__ float rsum16(float v) {
    v += dpp_f<0x128>(v); v += dpp_f<0x124>(v);
    v += dpp_f<0x122>(v); v += dpp_f<0x121>(v);
    return v;
}
__device__ __forceinline__ float rmax16(float v) {
    v = fmaxf(v, dpp_f<0x128>(v)); v = fmaxf(v, dpp_f<0x124>(v));
    v = fmaxf(v, dpp_f<0x122>(v)); v = fmaxf(v, dpp_f<0x121>(v));
    return v;
}

// ---- bijective XCD-chunked block remap (grid must be a multiple of 8) ----
// Default dispatch puts blockIdx i on XCD i%8; remapping work = (i%8)*per + i/8
// gives each XCD a CONTIGUOUS 1/8 of the point space -> DRAM-row + L2 locality.
__device__ __forceinline__ int xcd_swz(int blk, int nblk) {
    const int per = nblk >> 3;
    return (blk & 7) * per + (blk >> 3);
}

// ================= Kernel A: qk = Wk^T (q*scale), pp = Wp^T qk =================
// thread = (point, 16-channel quarter); no LDS.
__global__ __launch_bounds__(256, 4) void qkpp_kernel(
    const float* __restrict__ points, const float* __restrict__ Wk,
    const float* __restrict__ Wp, float* __restrict__ ws)
{
    const int tid = threadIdx.x;
    const int lane = tid & 63;
    const int q = lane >> 4;                            // quarter 0..3
    const int blk = xcd_swz(blockIdx.x, 1024);
    const int pt = blk * 64 + (tid >> 6) * 16 + (lane & 15);
    const int b = pt >> 14;
    const int n = pt & (Nn - 1);

    float qk[16];
#pragma unroll
    for (int k = 0; k < 16; ++k) qk[k] = 0.f;

    const float* prow = points + (size_t)b * 64 * Nn + n;
    const float* wkq = Wk + 16 * q;
#pragma unroll 4
    for (int c = 0; c < 64; ++c) {
        const float qv = prow[(size_t)c * Nn];          // coalesced (16n x4 dup -> 64B)
        const float4 w0 = *(const float4*)(wkq + c * 64 + 0);   // wave-broadcast (4 distinct)
        const float4 w1 = *(const float4*)(wkq + c * 64 + 4);
        const float4 w2 = *(const float4*)(wkq + c * 64 + 8);
        const float4 w3 = *(const float4*)(wkq + c * 64 + 12);
        qk[0]  = fmaf(qv, w0.x, qk[0]);  qk[1]  = fmaf(qv, w0.y, qk[1]);
        qk[2]  = fmaf(qv, w0.z, qk[2]);  qk[3]  = fmaf(qv, w0.w, qk[3]);
        qk[4]  = fmaf(qv, w1.x, qk[4]);  qk[5]  = fmaf(qv, w1.y, qk[5]);
        qk[6]  = fmaf(qv, w1.z, qk[6]);  qk[7]  = fmaf(qv, w1.w, qk[7]);
        qk[8]  = fmaf(qv, w2.x, qk[8]);  qk[9]  = fmaf(qv, w2.y, qk[9]);
        qk[10] = fmaf(qv, w2.z, qk[10]); qk[11] = fmaf(qv, w2.w, qk[11]);
        qk[12] = fmaf(qv, w3.x, qk[12]); qk[13] = fmaf(qv, w3.y, qk[13]);
        qk[14] = fmaf(qv, w3.z, qk[14]); qk[15] = fmaf(qv, w3.w, qk[15]);
    }
#pragma unroll
    for (int k = 0; k < 16; ++k) qk[k] *= 0.125f;       // fold SCALE

    // pp[j] = sum_c qk[c] * Wp[c][j]  (partial over own quarter, combine via shfl)
    float p0 = 0.f, p1 = 0.f, p2 = 0.f, p3 = 0.f;
#pragma unroll
    for (int k = 0; k < 16; ++k) {
        const float4 wp4 = *(const float4*)(Wp + (16 * q + k) * 4);
        p0 = fmaf(qk[k], wp4.x, p0);
        p1 = fmaf(qk[k], wp4.y, p1);
        p2 = fmaf(qk[k], wp4.z, p2);
        p3 = fmaf(qk[k], wp4.w, p3);
    }
    p0 += __shfl_xor(p0, 16); p0 += __shfl_xor(p0, 32);
    p1 += __shfl_xor(p1, 16); p1 += __shfl_xor(p1, 32);
    p2 += __shfl_xor(p2, 16); p2 += __shfl_xor(p2, 32);
    p3 += __shfl_xor(p3, 16); p3 += __shfl_xor(p3, 32);

    float* orow = ws + (size_t)pt * ST + 16 * q;
    ((float4*)orow)[0] = make_float4(qk[0],  qk[1],  qk[2],  qk[3]);
    ((float4*)orow)[1] = make_float4(qk[4],  qk[5],  qk[6],  qk[7]);
    ((float4*)orow)[2] = make_float4(qk[8],  qk[9],  qk[10], qk[11]);
    ((float4*)orow)[3] = make_float4(qk[12], qk[13], qk[14], qk[15]);
    if (q == 0)
        *(float4*)(ws + (size_t)pt * ST + 64) = make_float4(p0, p1, p2, p3);
}

// ====== Kernel B: logits + softmax + vbar + Wv matvec (fused; the streamer) ======
// wave = 4 points, lane = (nn, s); np loaded once into regs; Wv^T staged in LDS;
// out accumulated in the vbar loop (vbar[c] is live in all row lanes), stored direct.
__global__ __launch_bounds__(256, 4) void attn_out_kernel(
    const float* __restrict__ xyz, const float* __restrict__ nxyz,
    const float* __restrict__ npts, const float* __restrict__ Wv,
    const float* __restrict__ ws, float* __restrict__ out)
{
    __shared__ float wvT[67 * 68];              // [c][o], stride 68 (b128 reads 2-way = free)

    const int tid = threadIdx.x;
    // one-time Wv transpose-stage (coalesced global read)
    for (int idx = tid; idx < 64 * 67; idx += 256) {
        const int o = idx / 67, c = idx - o * 67;
        wvT[c * 68 + o] = Wv[idx];
    }
    __syncthreads();

    const int lane = tid & 63;
    const int s = lane & 15;
    const int nn = lane >> 4;
    const int blk = xcd_swz(blockIdx.x, 4096);
    const int gpt = blk * 16 + (tid >> 6) * 4;          // 4-point group base
    const int b = gpt >> 14;
    const int ng = gpt & (Nn - 1);
    const int pt = gpt + nn;                            // this lane's point

    const float* npb = npts + (size_t)(b * 64) * NS + (size_t)ng * 16 + lane;  // +c*NS

    // ---- np stream: 64 coalesced dword loads (256B/instr), ONCE, into regs ----
    float npv[64];
#pragma unroll
    for (int c = 0; c < 64; ++c) npv[c] = npb[(size_t)c * NS];

    // relative position (lane's (nn,s)); all loads fully coalesced (lane-linear)
    const float nx0 = nxyz[((size_t)(b * 3 + 0) * Nn + ng) * 16 + lane];
    const float nx1 = nxyz[((size_t)(b * 3 + 1) * Nn + ng) * 16 + lane];
    const float nx2 = nxyz[((size_t)(b * 3 + 2) * Nn + ng) * 16 + lane];
    const float x0 = xyz[(size_t)(b * 3 + 0) * Nn + ng + nn];
    const float x1 = xyz[(size_t)(b * 3 + 1) * Nn + ng + nn];
    const float x2 = xyz[(size_t)(b * 3 + 2) * Nn + ng + nn];
    const float d0 = x0 - nx0, d1 = x1 - nx1, d2 = x2 - nx2;
    const float dn = sqrtf(d0 * d0 + d1 * d1 + d2 * d2);

    const float* qrow = ws + (size_t)pt * ST;

    // ---- logit = qk . np  (np from regs; qk: 16B broadcast loads, L2-hot) ----
    float l0 = 0.f, l1 = 0.f, l2 = 0.f, l3 = 0.f;
#pragma unroll
    for (int jc = 0; jc < 16; ++jc) {
        const float4 qq = *(const float4*)(qrow + 4 * jc);
        l0 = fmaf(qq.x, npv[4 * jc + 0], l0);
        l1 = fmaf(qq.y, npv[4 * jc + 1], l1);
        l2 = fmaf(qq.z, npv[4 * jc + 2], l2);
        l3 = fmaf(qq.w, npv[4 * jc + 3], l3);
    }
    const float4 ppv = *(const float4*)(qrow + 64);
    float logit = (l0 + l1) + (l2 + l3);
    logit += ppv.x * d0 + ppv.y * d1 + ppv.z * d2 + ppv.w * dn;
    // (bp term constant in s -> cancels in softmax)

    // ---- softmax over s (pure DPP in rows of 16) ----
    const float mx = rmax16(logit);
    const float e = __expf(logit - mx);
    const float se = rsum16(e);
    const float attn = e / se;

    // ---- fused vbar + Wv matvec ----
    // rsum16 puts vbar[c] in ALL 16 lanes of row nn; lane (nn,s) owns o = 4s..4s+3.
    float a0 = 0.f, a1 = 0.f, a2 = 0.f, a3 = 0.f;
#pragma unroll
    for (int c = 0; c < 64; ++c) {
        const float r = rsum16(attn * npv[c]);                  // vbar[c, nn]
        const float4 wq = *(const float4*)&wvT[c * 68 + 4 * s]; // Wv[4s..4s+3][c]
        a0 = fmaf(r, wq.x, a0);
        a1 = fmaf(r, wq.y, a1);
        a2 = fmaf(r, wq.z, a2);
        a3 = fmaf(r, wq.w, a3);
    }
    {   // tail channels 64..66 (= tmp d0,d1,d2)
        const float t0 = rsum16(attn * d0);
        const float t1 = rsum16(attn * d1);
        const float t2 = rsum16(attn * d2);
        const float4 wA = *(const float4*)&wvT[64 * 68 + 4 * s];
        const float4 wB = *(const float4*)&wvT[65 * 68 + 4 * s];
        const float4 wC = *(const float4*)&wvT[66 * 68 + 4 * s];
        a0 = fmaf(t0, wA.x, a0); a1 = fmaf(t0, wA.y, a1);
        a2 = fmaf(t0, wA.z, a2); a3 = fmaf(t0, wA.w, a3);
        a0 = fmaf(t1, wB.x, a0); a1 = fmaf(t1, wB.y, a1);
        a2 = fmaf(t1, wB.z, a2); a3 = fmaf(t1, wB.w, a3);
        a0 = fmaf(t2, wC.x, a0); a1 = fmaf(t2, wC.y, a1);
        a2 = fmaf(t2, wC.z, a2); a3 = fmaf(t2, wC.w, a3);
    }

    // ---- direct stores: out[o = 4s+j][ng+nn]; 16 x 16B segments per instr;
    //      sibling waves + XCD-chunked neighbors complete 64B lines in one L2 ----
    float* ob = out + ((size_t)(b * 64 + 4 * s) * Nn) + ng + nn;
    ob[0]              = a0;
    ob[(size_t)Nn]     = a1;
    ob[(size_t)Nn * 2] = a2;
    ob[(size_t)Nn * 3] = a3;
}

extern "C" void kernel_launch(void* const* d_in, const int* in_sizes, int n_in,
                              void* d_out, int out_size, void* d_ws, size_t ws_size,
                              hipStream_t stream) {
    const float* xyz    = (const float*)d_in[0];
    const float* nxyz   = (const float*)d_in[1];
    const float* points = (const float*)d_in[2];
    const float* npts   = (const float*)d_in[3];
    const float* Wk     = (const float*)d_in[4];
    const float* Wv     = (const float*)d_in[5];
    const float* Wp     = (const float*)d_in[6];
    // d_in[7] = bp — unused: constant-in-s logit shift cancels in softmax
    float* out = (float*)d_out;
    float* ws = (float*)d_ws;   // [65536][68] fp32 = 17.8 MB, fully rewritten each call

    hipLaunchKernelGGL(qkpp_kernel,     dim3(1024), dim3(256), 0, stream,
                       points, Wk, Wp, ws);
    hipLaunchKernelGGL(attn_out_kernel, dim3(4096), dim3(256), 0, stream,
                       xyz, nxyz, npts, Wv, ws, out);
}

// Round 10
// 117.910 us; speedup vs baseline: 1.0392x; 1.0392x over previous
//
#include <hip/hip_runtime.h>
#include <math.h>

constexpr int Nn = 16384;
constexpr int ST = 68;                      // ws row stride (dwords): 64 qk + 4 pp
constexpr size_t NS = (size_t)Nn * 16;      // dwords per channel plane of npts

// ---- DPP helpers ----
template <int CTRL>
__device__ __forceinline__ float dpp_f(float x) {
    return __int_as_float(
        __builtin_amdgcn_update_dpp(0, __float_as_int(x), CTRL, 0xF, 0xF, false));
}
// quad (4-lane) butterflies: quad_perm [1,0,3,2]=0xB1, [2,3,0,1]=0x4E
__device__ __forceinline__ float qsum4(float v) {
    v += dpp_f<0xB1>(v);
    v += dpp_f<0x4E>(v);
    return v;
}
__device__ __forceinline__ float qmax4(float v) {
    v = fmaxf(v, dpp_f<0xB1>(v));
    v = fmaxf(v, dpp_f<0x4E>(v));
    return v;
}

// ================= Kernel A: qk = Wk^T (q*scale), pp = Wp^T qk =================
// thread = (point, 16-channel quarter); no LDS. (unchanged; isolate B's change)
__global__ __launch_bounds__(256, 4) void qkpp_kernel(
    const float* __restrict__ points, const float* __restrict__ Wk,
    const float* __restrict__ Wp, float* __restrict__ ws)
{
    const int tid = threadIdx.x;
    const int lane = tid & 63;
    const int q = lane >> 4;                            // quarter 0..3
    const int pt = blockIdx.x * 64 + (tid >> 6) * 16 + (lane & 15);
    const int b = pt >> 14;
    const int n = pt & (Nn - 1);

    float qk[16];
#pragma unroll
    for (int k = 0; k < 16; ++k) qk[k] = 0.f;

    const float* prow = points + (size_t)b * 64 * Nn + n;
    const float* wkq = Wk + 16 * q;
#pragma unroll 4
    for (int c = 0; c < 64; ++c) {
        const float qv = prow[(size_t)c * Nn];
        const float4 w0 = *(const float4*)(wkq + c * 64 + 0);
        const float4 w1 = *(const float4*)(wkq + c * 64 + 4);
        const float4 w2 = *(const float4*)(wkq + c * 64 + 8);
        const float4 w3 = *(const float4*)(wkq + c * 64 + 12);
        qk[0]  = fmaf(qv, w0.x, qk[0]);  qk[1]  = fmaf(qv, w0.y, qk[1]);
        qk[2]  = fmaf(qv, w0.z, qk[2]);  qk[3]  = fmaf(qv, w0.w, qk[3]);
        qk[4]  = fmaf(qv, w1.x, qk[4]);  qk[5]  = fmaf(qv, w1.y, qk[5]);
        qk[6]  = fmaf(qv, w1.z, qk[6]);  qk[7]  = fmaf(qv, w1.w, qk[7]);
        qk[8]  = fmaf(qv, w2.x, qk[8]);  qk[9]  = fmaf(qv, w2.y, qk[9]);
        qk[10] = fmaf(qv, w2.z, qk[10]); qk[11] = fmaf(qv, w2.w, qk[11]);
        qk[12] = fmaf(qv, w3.x, qk[12]); qk[13] = fmaf(qv, w3.y, qk[13]);
        qk[14] = fmaf(qv, w3.z, qk[14]); qk[15] = fmaf(qv, w3.w, qk[15]);
    }
#pragma unroll
    for (int k = 0; k < 16; ++k) qk[k] *= 0.125f;       // fold SCALE

    float p0 = 0.f, p1 = 0.f, p2 = 0.f, p3 = 0.f;
#pragma unroll
    for (int k = 0; k < 16; ++k) {
        const float4 wp4 = *(const float4*)(Wp + (16 * q + k) * 4);
        p0 = fmaf(qk[k], wp4.x, p0);
        p1 = fmaf(qk[k], wp4.y, p1);
        p2 = fmaf(qk[k], wp4.z, p2);
        p3 = fmaf(qk[k], wp4.w, p3);
    }
    p0 += __shfl_xor(p0, 16); p0 += __shfl_xor(p0, 32);
    p1 += __shfl_xor(p1, 16); p1 += __shfl_xor(p1, 32);
    p2 += __shfl_xor(p2, 16); p2 += __shfl_xor(p2, 32);
    p3 += __shfl_xor(p3, 16); p3 += __shfl_xor(p3, 32);

    float* orow = ws + (size_t)pt * ST + 16 * q;
    ((float4*)orow)[0] = make_float4(qk[0],  qk[1],  qk[2],  qk[3]);
    ((float4*)orow)[1] = make_float4(qk[4],  qk[5],  qk[6],  qk[7]);
    ((float4*)orow)[2] = make_float4(qk[8],  qk[9],  qk[10], qk[11]);
    ((float4*)orow)[3] = make_float4(qk[12], qk[13], qk[14], qk[15]);
    if (q == 0)
        *(float4*)(ws + (size_t)pt * ST + 64) = make_float4(p0, p1, p2, p3);
}

// ====== Kernel B: float4-vectorized streamer (G13 fix) ======
// block = 4 waves = 16 points; wave w owns channels 16w..16w+15.
// lane l: point p = l>>2, s-quad sq = l&3 (s = 4*sq..4*sq+3).
// All np / nxyz loads are 16B/lane x 64 lanes = 1KB contiguous per instr.
__global__ __launch_bounds__(256, 4) void attn_out_kernel(
    const float* __restrict__ xyz, const float* __restrict__ nxyz,
    const float* __restrict__ npts, const float* __restrict__ Wv,
    const float* __restrict__ ws, float* __restrict__ out)
{
    __shared__ float wvT[67 * 68];                     // [c][o], stride 68
    __shared__ __align__(16) float lexch[4][64][4];    // partial logits
    __shared__ float vbexch[67 * 17];                  // vbar exchange, stride 17

    const int tid = threadIdx.x;
    const int w = tid >> 6;
    const int l = tid & 63;
    const int p = l >> 2;
    const int sq = l & 3;
    const int gpt0 = blockIdx.x * 16;
    const int b = gpt0 >> 14;
    const int ng = gpt0 & (Nn - 1);

    // ---- issue all global loads FIRST (latency hides under wvT staging) ----
    const float* npb = npts + ((size_t)(b * 64 + 16 * w)) * NS + (size_t)ng * 16 + 4 * l;
    float4 npv4[16];
#pragma unroll
    for (int k = 0; k < 16; ++k) npv4[k] = *(const float4*)(npb + (size_t)k * NS);

    const float* qrow = ws + (size_t)(gpt0 + p) * ST + 16 * w;
    const float4 qqa = ((const float4*)qrow)[0];
    const float4 qqb = ((const float4*)qrow)[1];
    const float4 qqc = ((const float4*)qrow)[2];
    const float4 qqd = ((const float4*)qrow)[3];

    float4 d04, d14, d24, dn4, pp4;
    if (w == 3) {   // pos handled only by wave 3 (no duplicated traffic)
        const float4 nx0 = *(const float4*)(nxyz + ((size_t)(b * 3 + 0) * Nn + ng) * 16 + 4 * l);
        const float4 nx1 = *(const float4*)(nxyz + ((size_t)(b * 3 + 1) * Nn + ng) * 16 + 4 * l);
        const float4 nx2 = *(const float4*)(nxyz + ((size_t)(b * 3 + 2) * Nn + ng) * 16 + 4 * l);
        const float x0 = xyz[(size_t)(b * 3 + 0) * Nn + ng + p];
        const float x1 = xyz[(size_t)(b * 3 + 1) * Nn + ng + p];
        const float x2 = xyz[(size_t)(b * 3 + 2) * Nn + ng + p];
        d04 = make_float4(x0 - nx0.x, x0 - nx0.y, x0 - nx0.z, x0 - nx0.w);
        d14 = make_float4(x1 - nx1.x, x1 - nx1.y, x1 - nx1.z, x1 - nx1.w);
        d24 = make_float4(x2 - nx2.x, x2 - nx2.y, x2 - nx2.z, x2 - nx2.w);
        dn4 = make_float4(sqrtf(d04.x * d04.x + d14.x * d14.x + d24.x * d24.x),
                          sqrtf(d04.y * d04.y + d14.y * d14.y + d24.y * d24.y),
                          sqrtf(d04.z * d04.z + d14.z * d14.z + d24.z * d24.z),
                          sqrtf(d04.w * d04.w + d14.w * d14.w + d24.w * d24.w));
        pp4 = *(const float4*)(ws + (size_t)(gpt0 + p) * ST + 64);
    }

    // ---- one-time Wv transpose-stage ----
    for (int idx = tid; idx < 64 * 67; idx += 256) {
        const int o = idx / 67, c = idx - o * 67;
        wvT[c * 68 + o] = Wv[idx];
    }

    // ---- partial logit over own 16 channels (4 s-values per lane) ----
    const float qks[16] = {qqa.x, qqa.y, qqa.z, qqa.w, qqb.x, qqb.y, qqb.z, qqb.w,
                           qqc.x, qqc.y, qqc.z, qqc.w, qqd.x, qqd.y, qqd.z, qqd.w};
    float4 lp = make_float4(0.f, 0.f, 0.f, 0.f);
#pragma unroll
    for (int k = 0; k < 16; ++k) {
        lp.x = fmaf(qks[k], npv4[k].x, lp.x);
        lp.y = fmaf(qks[k], npv4[k].y, lp.y);
        lp.z = fmaf(qks[k], npv4[k].z, lp.z);
        lp.w = fmaf(qks[k], npv4[k].w, lp.w);
    }
    if (w == 3) {   // + pp . pos   (bp term constant in s -> cancels in softmax)
        lp.x += pp4.x * d04.x + pp4.y * d14.x + pp4.z * d24.x + pp4.w * dn4.x;
        lp.y += pp4.x * d04.y + pp4.y * d14.y + pp4.z * d24.y + pp4.w * dn4.y;
        lp.z += pp4.x * d04.z + pp4.y * d14.z + pp4.z * d24.z + pp4.w * dn4.z;
        lp.w += pp4.x * d04.w + pp4.y * d14.w + pp4.z * d24.w + pp4.w * dn4.w;
    }

    // ---- combine partial logits across the 4 waves ----
    __syncthreads();                        // wvT staged (and lexch free)
    *(float4*)&lexch[w][l][0] = lp;
    __syncthreads();
    const float4 g0 = *(const float4*)&lexch[0][l][0];
    const float4 g1 = *(const float4*)&lexch[1][l][0];
    const float4 g2 = *(const float4*)&lexch[2][l][0];
    const float4 g3 = *(const float4*)&lexch[3][l][0];
    const float4 lg = make_float4(g0.x + g1.x + g2.x + g3.x,
                                  g0.y + g1.y + g2.y + g3.y,
                                  g0.z + g1.z + g2.z + g3.z,
                                  g0.w + g1.w + g2.w + g3.w);

    // ---- softmax over 16 s: in-lane(4) + quad reduce, pure DPP ----
    float mx = fmaxf(fmaxf(lg.x, lg.y), fmaxf(lg.z, lg.w));
    mx = qmax4(mx);
    const float e0 = __expf(lg.x - mx), e1 = __expf(lg.y - mx);
    const float e2 = __expf(lg.z - mx), e3 = __expf(lg.w - mx);
    const float se = qsum4((e0 + e1) + (e2 + e3));
    const float inv = 1.0f / se;
    const float at0 = e0 * inv, at1 = e1 * inv, at2 = e2 * inv, at3 = e3 * inv;

    // ---- vbar over own channels -> LDS exchange ----
#pragma unroll
    for (int k = 0; k < 16; ++k) {
        float v = at0 * npv4[k].x + at1 * npv4[k].y + at2 * npv4[k].z + at3 * npv4[k].w;
        v = qsum4(v);                                   // vbar[16w+k][p] in all 4 quad lanes
        if (sq == (k & 3)) vbexch[(16 * w + k) * 17 + p] = v;
    }
    if (w == 3) {   // tail channels 64..66 (= tmp d0,d1,d2)
        const float t0 = qsum4(at0 * d04.x + at1 * d04.y + at2 * d04.z + at3 * d04.w);
        const float t1 = qsum4(at0 * d14.x + at1 * d14.y + at2 * d14.z + at3 * d14.w);
        const float t2 = qsum4(at0 * d24.x + at1 * d24.y + at2 * d24.z + at3 * d24.w);
        if (sq == 0) vbexch[64 * 17 + p] = t0;
        else if (sq == 1) vbexch[65 * 17 + p] = t1;
        else if (sq == 2) vbexch[66 * 17 + p] = t2;
    }
    __syncthreads();

    // ---- out matvec: wave w covers o = 16w..16w+15; lane -> o-quad 16w+4sq.. ----
    float4 oa = make_float4(0.f, 0.f, 0.f, 0.f);
#pragma unroll
    for (int c = 0; c < 67; ++c) {
        const float vb = vbexch[c * 17 + p];                        // quad-broadcast
        const float4 wq = *(const float4*)&wvT[c * 68 + 16 * w + 4 * sq];
        oa.x = fmaf(vb, wq.x, oa.x);
        oa.y = fmaf(vb, wq.y, oa.y);
        oa.z = fmaf(vb, wq.z, oa.z);
        oa.w = fmaf(vb, wq.w, oa.w);
    }

    // stores: rows o=16w+4sq+e, col ng+p -> 4 x 64B segments per instruction
    float* ob = out + ((size_t)(b * 64 + 16 * w + 4 * sq)) * Nn + ng + p;
    ob[0]              = oa.x;
    ob[(size_t)Nn]     = oa.y;
    ob[(size_t)Nn * 2] = oa.z;
    ob[(size_t)Nn * 3] = oa.w;
}

extern "C" void kernel_launch(void* const* d_in, const int* in_sizes, int n_in,
                              void* d_out, int out_size, void* d_ws, size_t ws_size,
                              hipStream_t stream) {
    const float* xyz    = (const float*)d_in[0];
    const float* nxyz   = (const float*)d_in[1];
    const float* points = (const float*)d_in[2];
    const float* npts   = (const float*)d_in[3];
    const float* Wk     = (const float*)d_in[4];
    const float* Wv     = (const float*)d_in[5];
    const float* Wp     = (const float*)d_in[6];
    // d_in[7] = bp — unused: constant-in-s logit shift cancels in softmax
    float* out = (float*)d_out;
    float* ws = (float*)d_ws;   // [65536][68] fp32 = 17.8 MB, fully rewritten each call

    hipLaunchKernelGGL(qkpp_kernel,     dim3(1024), dim3(256), 0, stream,
                       points, Wk, Wp, ws);
    hipLaunchKernelGGL(attn_out_kernel, dim3(4096), dim3(256), 0, stream,
                       xyz, nxyz, npts, Wv, ws, out);
}